// Round 13
// baseline (1148.013 us; speedup 1.0000x reference)
//
#include <hip/hip_runtime.h>
#include <hip/hip_bf16.h>
#include <hip/hip_fp16.h>

#define NN 50000
#define NNP 50048          // padded node count (782 * 64)
#define EE 800000
#define BB 1000
#define NB 2048            // radial table bins over [0, RTMAX]
#define RTMAX 10.0f
#define WPB 4              // waves per block in agg; each wave owns 2 nodes

__device__ __forceinline__ float silu(float x){ return x / (1.0f + __expf(-x)); }

// ---------------- combined projection weights: wpc[L][k][112] ----------------
__global__ __launch_bounds__(256) void prep_w(
    const float* __restrict__ wp0, const float* __restrict__ wp1, const float* __restrict__ wp2,
    float* __restrict__ wpc)
{
    int t = blockIdx.x * 256 + threadIdx.x;
    if (t >= 4*64*112) return;
    int L = t / (64*112); int r = t % (64*112); int k = r / 112; int j = r % 112;
    float w;
    if (j < 64)      w = wp0[L*64*64 + k*64 + j];
    else if (j < 96) w = wp1[L*64*32 + k*32 + (j-64)];
    else             w = wp2[L*64*16 + k*16 + (j-96)];
    wpc[t] = w;
}

// transposed weight sets for the scalar-operand GEMV update
// s0T[L][j][k], s1T[L][j][m], s2T[L][j][m], wpcT[L][m][k]
__global__ __launch_bounds__(256) void prep_wT(
    const float* __restrict__ s0, const float* __restrict__ s1, const float* __restrict__ s2,
    const float* __restrict__ wpc,
    float* __restrict__ s0T, float* __restrict__ s1T, float* __restrict__ s2T,
    float* __restrict__ wpcT)
{
    int t = blockIdx.x*256 + threadIdx.x;
    if (t < 4*4096) {
        int L = t / 4096; int r = t % 4096; int j = r / 64; int k = r % 64;
        s0T[t] = s0[L*4096 + k*64 + j];
    }
    if (t < 4*1024) {
        int L = t / 1024; int r = t % 1024; int j = r / 32; int m = r % 32;
        s1T[t] = s1[L*1024 + m*32 + j];
    }
    if (t < 4*256) {
        int L = t / 256; int r = t % 256; int j = r / 16; int m = r % 16;
        s2T[t] = s2[L*256 + m*16 + j];
    }
    if (t < 4*7168) {
        int L = t / 7168; int r = t % 7168; int m = r / 64; int k = r % 64;
        wpcT[t] = wpc[L*7168 + k*112 + m];
    }
}

// prodTable[z][j] = sum_k emb[z][k] * wpc_L0[k][j]
__global__ __launch_bounds__(128) void prep_pt(
    const float* __restrict__ emb, const float* __restrict__ wpc, float* __restrict__ pt)
{
    int zz = blockIdx.x; int j = threadIdx.x;
    __shared__ float er[64];
    if (j < 64) er[j] = emb[zz*64 + j];
    __syncthreads();
    if (j >= 112) return;
    float s = 0.0f;
    #pragma unroll
    for (int k = 0; k < 64; k++) s += er[k] * wpc[k*112 + j];
    pt[zz*112 + j] = s;
}

// ---------------- CSR build ----------------
__global__ __launch_bounds__(256) void hist_kernel(const int* __restrict__ ei, int* __restrict__ deg)
{
    int e = blockIdx.x * 256 + threadIdx.x;
    if (e < EE) atomicAdd(&deg[ei[EE + e]], 1);
}

__global__ __launch_bounds__(256) void scan1(const int* __restrict__ deg,
                                             int* __restrict__ start, int* __restrict__ bsum)
{
    __shared__ int buf[256];
    int tid = threadIdx.x;
    int i = blockIdx.x*256 + tid;
    int v = (i < NN) ? deg[i] : 0;
    buf[tid] = v; __syncthreads();
    #pragma unroll
    for (int off = 1; off < 256; off <<= 1) {
        int t = (tid >= off) ? buf[tid-off] : 0;
        __syncthreads(); buf[tid] += t; __syncthreads();
    }
    if (i < NN) start[i] = buf[tid] - v;
    if (tid == 255) bsum[blockIdx.x] = buf[255];
}
__global__ __launch_bounds__(256) void scan2(int* __restrict__ bsum, int nb)
{
    __shared__ int buf[256];
    int tid = threadIdx.x;
    int v = (tid < nb) ? bsum[tid] : 0;
    buf[tid] = v; __syncthreads();
    #pragma unroll
    for (int off = 1; off < 256; off <<= 1) {
        int t = (tid >= off) ? buf[tid-off] : 0;
        __syncthreads(); buf[tid] += t; __syncthreads();
    }
    if (tid < nb) bsum[tid] = buf[tid] - v;
}
__global__ __launch_bounds__(256) void scan3(int* __restrict__ start, const int* __restrict__ bsum,
                                             int* __restrict__ cursor)
{
    int i = blockIdx.x*256 + threadIdx.x;
    if (i < NN) { int v = start[i] + bsum[blockIdx.x]; start[i] = v; cursor[i] = v; }
    if (i == 0) start[NN] = EE;
}

// ---------------- fused geometry + scatter: 16B packed edge record ----------------
__global__ __launch_bounds__(256) void geom_scatter(
    const float* __restrict__ pos, const int* __restrict__ ei, const float* __restrict__ shift,
    int* __restrict__ cursor, int4* __restrict__ edata)
{
    int e = blockIdx.x * 256 + threadIdx.x;
    if (e >= EE) return;
    int s = ei[e], d = ei[EE + e];
    float vx = pos[d*3+0] - pos[s*3+0] + shift[e*3+0];
    float vy = pos[d*3+1] - pos[s*3+1] + shift[e*3+1];
    float vz = pos[d*3+2] - pos[s*3+2] + shift[e*3+2];
    float r = sqrtf(vx*vx + vy*vy + vz*vz);
    float inv = 1.0f / (r + 1e-9f);
    float x = vx*inv, y = vy*inv, z = vz*inv;
    int p = atomicAdd(&cursor[d], 1);
    __half2 xy = __floats2half2_rn(x, y);
    __half2 z0 = __floats2half2_rn(z, 0.0f);
    int4 rec;
    rec.x = s;
    rec.y = __float_as_int(r);
    rec.z = *(const int*)&xy;
    rec.w = *(const int*)&z0;
    edata[p] = rec;
}

// ---------------- radial features on the bin grid (f32, NB+1 bins) ----------------
__global__ __launch_bounds__(128) void build_rf(
    const float* __restrict__ rw1, const float* __restrict__ rb1,
    const float* __restrict__ rw2, const float* __restrict__ rb2,
    float* __restrict__ rfall)
{
    int idx = blockIdx.x;
    int L = idx / (NB+1), bin = idx % (NB+1);
    float r = bin * (RTMAX / NB);
    int t = threadIdx.x;
    __shared__ float h1[64];
    if (t < 64) {
        float s = rb1[L*64 + t];
        #pragma unroll
        for (int i = 0; i < 10; i++) { float a = 1.8f*r - (float)i; s += __expf(-a*a) * rw1[L*640 + i*64 + t]; }
        h1[t] = silu(s);
    }
    __syncthreads();
    if (t < 112) {
        float s = rb2[L*112 + t];
        #pragma unroll 8
        for (int k = 0; k < 64; k++) s += h1[k] * rw2[(size_t)L*7168 + k*112 + t];
        rfall[(size_t)idx*112 + t] = s * 0.25f;
    }
}

// pack: tabpack[L][bin][lane] = 8B { half2(A_lo,A_hi), half2(B_lo,B_hi) }
__global__ __launch_bounds__(256) void pack_tab(
    const float* __restrict__ rfall, uint2* __restrict__ tabpack)
{
    int t = blockIdx.x*256 + threadIdx.x;
    if (t >= 4*NB*64) return;
    int lane = t & 63;
    int rest = t >> 6;
    int L = rest / NB, bin = rest % NB;
    const float* lo = rfall + (size_t)(L*(NB+1) + bin)*112;
    const float* hi = lo + 112;
    float aLo = lo[lane], aHi = hi[lane];
    float bLo = (lane < 48) ? lo[64+lane] : 0.0f;
    float bHi = (lane < 48) ? hi[64+lane] : 0.0f;
    __half2 ha = __floats2half2_rn(aLo, aHi);
    __half2 hb = __floats2half2_rn(bLo, bHi);
    uint2 o;
    o.x = *(const unsigned*)&ha;
    o.y = *(const unsigned*)&hb;
    tabpack[t] = o;
}

// ---------------- init: h_T (transposed) and packed P0 ----------------
__global__ __launch_bounds__(256) void init_hT(
    const int* __restrict__ z, const float* __restrict__ emb, float* __restrict__ hT)
{
    int lane = threadIdx.x & 63; int w = threadIdx.x >> 6;
    int n = blockIdx.x*64 + lane;
    bool valid = n < NN;
    int zz = valid ? z[n] : 0;
    for (int c = w; c < 240; c += 4) {
        float v = (c < 64) ? emb[zz*64 + c] : 0.0f;
        if (valid) hT[(size_t)c*NNP + n] = v;
    }
}

__global__ __launch_bounds__(64) void init_P(
    const int* __restrict__ z, const float* __restrict__ pt, unsigned* __restrict__ Ppack)
{
    int n = blockIdx.x; int j = threadIdx.x;
    int zz = z[n];
    float a = pt[zz*112 + j];
    float b = (j < 48) ? pt[zz*112 + 64 + j] : 0.0f;
    __half2 hp = __floats2half2_rn(a, b);
    Ppack[(size_t)n*64 + j] = *(const unsigned*)&hp;
}

// ---------------- aggregation (R12 edge loop): 2 nodes per wave -> acc rows ----------------
__global__ __launch_bounds__(256) void agg_kernel(
    const unsigned* __restrict__ Ppack, const int4* __restrict__ edata,
    const int* __restrict__ start, const uint2* __restrict__ tabp,
    float* __restrict__ acc)
{
    int lane = threadIdx.x & 63;
    int wv   = threadIdx.x >> 6;
    int nA = blockIdx.x*(WPB*2) + wv*2;
    int nB = nA + 1;

    __shared__ float ebuf_s[WPB][2][16*12];
    __shared__ float accb_s[WPB][2][240];

    int p0A = start[nA], p1A = start[nA+1];
    int p1B = start[nB+1];
    float aS_A = 0.0f, aS_B = 0.0f;
    float aB_A[5] = {0,0,0,0,0};
    float aB_B[5] = {0,0,0,0,0};
    bool hasB = lane < 48;
    int sbase = (lane < 32) ? 0 : 3;
    int ncomp = (lane < 32) ? 3 : 5;
    const float binscale = (float)NB / RTMAX;
    const float C3 = 1.7320508075688772f, C15 = 3.872983346207417f, C5 = 2.23606797749979f;

    const char* tabc = (const char*)tabp;
    const char* Pc   = (const char*)Ppack;

    int baseA = p0A, baseB = p1A;
    while (baseA < p1A || baseB < p1B) {
        int cntA = p1A - baseA; cntA = cntA < 0 ? 0 : (cntA > 16 ? 16 : cntA);
        int cntB = p1B - baseB; cntB = cntB < 0 ? 0 : (cntB > 16 ? 16 : cntB);
        #pragma unroll
        for (int s = 0; s < 2; s++) {
            int cnt  = s ? cntB : cntA;
            int base = s ? baseB : baseA;
            if (lane < cnt) {
                int4 rec = edata[base + lane];
                float f = fminf(__int_as_float(rec.y) * binscale, (float)NB - 0.5f);
                int b = (int)f;
                float fr = f - (float)b;
                __half2 xy = *(const __half2*)&rec.z;
                __half2 z0 = *(const __half2*)&rec.w;
                float x = __half2float(xy.x), y = __half2float(xy.y), z = __half2float(z0.x);
                float4* v4 = (float4*)(ebuf_s[wv][s] + lane*12);
                v4[0] = make_float4(__int_as_float(b*512), __int_as_float(rec.x*256), fr, 0.0f);
                v4[1] = make_float4(C3*x, C3*y, C3*z, C15*x*y);
                v4[2] = make_float4(C15*y*z, 0.5f*C5*(3.0f*z*z - 1.0f), C15*x*z, 0.5f*C15*(x*x - y*y));
            }
        }
        asm volatile("s_waitcnt lgkmcnt(0)" ::: "memory");
        #pragma unroll
        for (int s = 0; s < 2; s++) {
            int cnt = s ? cntB : cntA;
            const float* eb = ebuf_s[wv][s];
            float aS_l = 0.0f;
            float aB_l[5] = {0,0,0,0,0};
            #pragma unroll 4
            for (int e = 0; e < 16; e++) {
                if (e < cnt) {
                    const float* ep = eb + e*12;
                    int boff = __float_as_int(ep[0]);
                    int poff = __float_as_int(ep[1]);
                    float fr = ep[2];
                    uint2 tt = *(const uint2*)(tabc + boff + lane*8);
                    unsigned pv = *(const unsigned*)(Pc + poff + lane*4);
                    __half2 ha = *(const __half2*)&tt.x;
                    __half2 hp = *(const __half2*)&pv;
                    float alo = __half2float(ha.x), ahi = __half2float(ha.y);
                    float pA  = __half2float(hp.x);
                    aS_l += (alo + (ahi - alo)*fr) * pA;
                    if (hasB) {
                        __half2 hb = *(const __half2*)&tt.y;
                        float blo = __half2float(hb.x), bhi = __half2float(hb.y);
                        float pB  = __half2float(hp.y);
                        float msg = (blo + (bhi - blo)*fr) * pB;
                        #pragma unroll
                        for (int d = 0; d < 5; d++)
                            if (d < ncomp) aB_l[d] += msg * ep[4 + sbase + d];
                    }
                }
            }
            if (s == 0) {
                aS_A += aS_l;
                #pragma unroll
                for (int d = 0; d < 5; d++) aB_A[d] += aB_l[d];
            } else {
                aS_B += aS_l;
                #pragma unroll
                for (int d = 0; d < 5; d++) aB_B[d] += aB_l[d];
            }
        }
        asm volatile("s_waitcnt lgkmcnt(0)" ::: "memory");
        baseA += 16; baseB += 16;
    }

    #pragma unroll
    for (int s = 0; s < 2; s++) {
        float* ab = accb_s[wv][s];
        ab[lane] = s ? aS_B : aS_A;
        const float* aB = s ? aB_B : aB_A;
        if (lane < 32) {
            #pragma unroll
            for (int d = 0; d < 3; d++) ab[64 + lane*3 + d] = aB[d];
        } else if (lane < 48) {
            #pragma unroll
            for (int d = 0; d < 5; d++) ab[160 + (lane-32)*5 + d] = aB[d];
        }
    }
    asm volatile("s_waitcnt lgkmcnt(0)" ::: "memory");
    #pragma unroll
    for (int s = 0; s < 2; s++) {
        float* arow = acc + (size_t)(nA + s)*240;
        const float* ab = accb_s[wv][s];
        #pragma unroll
        for (int c = lane; c < 240; c += 64) arow[c] = ab[c];
    }
}

// ---------------- update: lane=node batched GEMV, weights via scalar path ----------------
// block = 256 threads = 4 waves; 64 nodes (lane = node). h_T updated in place:
// phase0 loads all inputs to regs, barrier, phase1 computes+stores, barrier,
// phase2 wpc quarters from LDS sn, barrier, P flush.
__global__ __launch_bounds__(256) void update_kernel(
    float* __restrict__ hT, const float* __restrict__ acc,
    const float* __restrict__ s0T, const float* __restrict__ s1T, const float* __restrict__ s2T,
    const float* __restrict__ wpcT_next, unsigned* __restrict__ Pnext, int hasNext)
{
    __shared__ __half snbuf[64*66];
    __shared__ __half ph[64*116];
    int tid = threadIdx.x, lane = tid & 63, w = tid >> 6;
    int n0 = blockIdx.x*64; int n = n0 + lane;
    bool valid = n < NN;
    const float* accrow = acc + (size_t)n*240;

    // ---- phase 0: load inputs ----
    float hs[64];                // w0,w1
    float hv0[32], hv1[32];      // w2 (comps 0,1) / w3 (comp 2 in hv0)
    float ht0[16], ht1[16], ht2[16], ht3[16], ht4[16];   // w3
    if (w < 2) {
        #pragma unroll
        for (int k = 0; k < 64; k++) hs[k] = hT[(size_t)k*NNP + n];
    } else if (w == 2) {
        #pragma unroll
        for (int m = 0; m < 32; m++) hv0[m] = hT[(size_t)(64 + 3*m + 0)*NNP + n];
        #pragma unroll
        for (int m = 0; m < 32; m++) hv1[m] = hT[(size_t)(64 + 3*m + 1)*NNP + n];
    } else {
        #pragma unroll
        for (int m = 0; m < 32; m++) hv0[m] = hT[(size_t)(64 + 3*m + 2)*NNP + n];
        #pragma unroll
        for (int m = 0; m < 16; m++) ht0[m] = hT[(size_t)(160 + 5*m + 0)*NNP + n];
        #pragma unroll
        for (int m = 0; m < 16; m++) ht1[m] = hT[(size_t)(160 + 5*m + 1)*NNP + n];
        #pragma unroll
        for (int m = 0; m < 16; m++) ht2[m] = hT[(size_t)(160 + 5*m + 2)*NNP + n];
        #pragma unroll
        for (int m = 0; m < 16; m++) ht3[m] = hT[(size_t)(160 + 5*m + 3)*NNP + n];
        #pragma unroll
        for (int m = 0; m < 16; m++) ht4[m] = hT[(size_t)(160 + 5*m + 4)*NNP + n];
    }
    __syncthreads();

    // ---- phase 1: compute + store ----
    if (w < 2) {
        int j0 = 32*w;
        #pragma unroll 1
        for (int j = j0; j < j0 + 32; j++) {
            const float* wr = s0T + j*64;     // wave-uniform -> scalar loads
            float t0 = 0.0f, t1 = 0.0f;
            #pragma unroll
            for (int k = 0; k < 64; k += 2) { t0 += hs[k]*wr[k]; t1 += hs[k+1]*wr[k+1]; }
            float u = silu(t0 + t1 + accrow[j]);
            if (valid) hT[(size_t)j*NNP + n] = u;
            snbuf[lane*66 + j] = __float2half(u);
        }
    } else if (w == 2) {
        #pragma unroll 1
        for (int j = 0; j < 32; j++) {
            const float* wr = s1T + j*32;
            float t0 = 0.0f, t1 = 0.0f;
            #pragma unroll
            for (int m = 0; m < 32; m += 2) { t0 += hv0[m]*wr[m]; t1 += hv0[m+1]*wr[m+1]; }
            float v = t0 + t1 + accrow[64 + 3*j + 0];
            if (valid) hT[(size_t)(64 + 3*j + 0)*NNP + n] = v;
        }
        #pragma unroll 1
        for (int j = 0; j < 32; j++) {
            const float* wr = s1T + j*32;
            float t0 = 0.0f, t1 = 0.0f;
            #pragma unroll
            for (int m = 0; m < 32; m += 2) { t0 += hv1[m]*wr[m]; t1 += hv1[m+1]*wr[m+1]; }
            float v = t0 + t1 + accrow[64 + 3*j + 1];
            if (valid) hT[(size_t)(64 + 3*j + 1)*NNP + n] = v;
        }
    } else {
        #pragma unroll 1
        for (int j = 0; j < 32; j++) {
            const float* wr = s1T + j*32;
            float t0 = 0.0f, t1 = 0.0f;
            #pragma unroll
            for (int m = 0; m < 32; m += 2) { t0 += hv0[m]*wr[m]; t1 += hv0[m+1]*wr[m+1]; }
            float v = t0 + t1 + accrow[64 + 3*j + 2];
            if (valid) hT[(size_t)(64 + 3*j + 2)*NNP + n] = v;
        }
        #pragma unroll 1
        for (int j = 0; j < 16; j++) {
            const float* wr = s2T + j*16;
            float t0 = 0.0f;
            #pragma unroll
            for (int m = 0; m < 16; m++) t0 += ht0[m]*wr[m];
            if (valid) hT[(size_t)(160 + 5*j + 0)*NNP + n] = t0 + accrow[160 + 5*j + 0];
        }
        #pragma unroll 1
        for (int j = 0; j < 16; j++) {
            const float* wr = s2T + j*16;
            float t0 = 0.0f;
            #pragma unroll
            for (int m = 0; m < 16; m++) t0 += ht1[m]*wr[m];
            if (valid) hT[(size_t)(160 + 5*j + 1)*NNP + n] = t0 + accrow[160 + 5*j + 1];
        }
        #pragma unroll 1
        for (int j = 0; j < 16; j++) {
            const float* wr = s2T + j*16;
            float t0 = 0.0f;
            #pragma unroll
            for (int m = 0; m < 16; m++) t0 += ht2[m]*wr[m];
            if (valid) hT[(size_t)(160 + 5*j + 2)*NNP + n] = t0 + accrow[160 + 5*j + 2];
        }
        #pragma unroll 1
        for (int j = 0; j < 16; j++) {
            const float* wr = s2T + j*16;
            float t0 = 0.0f;
            #pragma unroll
            for (int m = 0; m < 16; m++) t0 += ht3[m]*wr[m];
            if (valid) hT[(size_t)(160 + 5*j + 3)*NNP + n] = t0 + accrow[160 + 5*j + 3];
        }
        #pragma unroll 1
        for (int j = 0; j < 16; j++) {
            const float* wr = s2T + j*16;
            float t0 = 0.0f;
            #pragma unroll
            for (int m = 0; m < 16; m++) t0 += ht4[m]*wr[m];
            if (valid) hT[(size_t)(160 + 5*j + 4)*NNP + n] = t0 + accrow[160 + 5*j + 4];
        }
    }
    __syncthreads();

    // ---- phase 2: next-layer projection (wpc quarters) ----
    if (hasNext) {
        float snr[64];
        #pragma unroll
        for (int k = 0; k < 64; k++) snr[k] = __half2float(snbuf[lane*66 + k]);
        int m0 = 28*w;
        #pragma unroll 1
        for (int m = m0; m < m0 + 28; m++) {
            const float* wr = wpcT_next + m*64;
            float t0 = 0.0f, t1 = 0.0f;
            #pragma unroll
            for (int k = 0; k < 64; k += 2) { t0 += snr[k]*wr[k]; t1 += snr[k+1]*wr[k+1]; }
            ph[lane*116 + m] = __float2half(t0 + t1);
        }
    }
    __syncthreads();
    if (hasNext) {
        #pragma unroll 1
        for (int idx = tid; idx < 64*64; idx += 256) {
            int node = idx >> 6, m = idx & 63;
            __half a = ph[node*116 + m];
            __half b = (m < 48) ? ph[node*116 + 64 + m] : __float2half(0.0f);
            __half2 hp; hp.x = a; hp.y = b;
            if (n0 + node < NN) Pnext[(size_t)(n0 + node)*64 + m] = *(const unsigned*)&hp;
        }
    }
}

// ---------------- readout A ----------------
__global__ __launch_bounds__(64) void readout_a(
    const float* __restrict__ hT, const float* __restrict__ wq, const float* __restrict__ wk,
    float* __restrict__ kq, float* __restrict__ zr)
{
    int b = blockIdx.x; int j = threadIdx.x;
    int na = 50 * b;
    __shared__ float sa[64], qv[64];
    sa[j] = hT[(size_t)j*NNP + na];
    __syncthreads();
    float q = 0.0f;
    #pragma unroll 8
    for (int k = 0; k < 64; k++) q += sa[k] * wq[k*64 + j];
    qv[j] = q;
    zr[b*176 + j] = sa[j];
    if (j < 32) {
        float nv = 0.0f;
        #pragma unroll
        for (int c = 0; c < 3; c++) { float v = hT[(size_t)(64 + j*3 + c)*NNP + na]; nv += v*v; }
        zr[b*176 + 128 + j] = nv;
    }
    if (j < 16) {
        float nt = 0.0f;
        #pragma unroll
        for (int c = 0; c < 5; c++) { float v = hT[(size_t)(160 + j*5 + c)*NNP + na]; nt += v*v; }
        zr[b*176 + 160 + j] = nt;
    }
    __syncthreads();
    float s = 0.0f;
    #pragma unroll 8
    for (int jj = 0; jj < 64; jj++) s += wk[j*64 + jj] * qv[jj];
    kq[b*64 + j] = s;
}

// ---------------- readout B ----------------
__global__ __launch_bounds__(64) void readout_b(
    const float* __restrict__ hT, const float* __restrict__ kq, const float* __restrict__ wv,
    float* __restrict__ zr)
{
    int b = blockIdx.x; int lane = threadIdx.x;
    __shared__ float hblk[64][51];
    __shared__ float at[64], hbar[64];
    #pragma unroll 1
    for (int k = 0; k < 64; k++)
        if (lane < 50) hblk[k][lane] = hT[(size_t)k*NNP + 50*b + lane];
    __syncthreads();
    const float* kqb = kq + b*64;
    float logit = -1e30f;
    if (lane < 50) {
        float t = 0.0f;
        #pragma unroll 8
        for (int k = 0; k < 64; k++) t += hblk[k][lane] * kqb[k];
        logit = t * 0.125f;
    }
    float mx = logit;
    for (int o = 32; o; o >>= 1) mx = fmaxf(mx, __shfl_xor(mx, o));
    float ex = (lane < 50) ? __expf(logit - mx) : 0.0f;
    float den = ex;
    for (int o = 32; o; o >>= 1) den += __shfl_xor(den, o);
    at[lane] = ex / den;
    __syncthreads();
    float hb = 0.0f;
    #pragma unroll 1
    for (int i = 0; i < 50; i++) hb += at[i] * hblk[lane][i];
    hbar[lane] = hb;
    __syncthreads();
    float c = 0.0f;
    #pragma unroll 8
    for (int k = 0; k < 64; k++) c += hbar[k] * wv[k*64 + lane];
    zr[b*176 + 64 + lane] = c;
}

// ---------------- readout C ----------------
__global__ __launch_bounds__(128) void readout_c(
    const float* __restrict__ zr, const float* __restrict__ m1, const float* __restrict__ mb1,
    const float* __restrict__ m2, const float* __restrict__ mb2, float* __restrict__ out)
{
    int b = blockIdx.x; int j = threadIdx.x;
    __shared__ float z[176], tb[128];
    for (int t = j; t < 176; t += 128) z[t] = zr[b*176 + t];
    __syncthreads();
    float a = mb1[j];
    #pragma unroll 8
    for (int k = 0; k < 176; k++) a += z[k] * m1[k*128 + j];
    tb[j] = silu(a);
    __syncthreads();
    float o = mb2[j];
    #pragma unroll 8
    for (int k = 0; k < 128; k++) o += tb[k] * m2[k*128 + j];
    out[b*128 + j] = o;
}

extern "C" void kernel_launch(void* const* d_in, const int* in_sizes, int n_in,
                              void* d_out, int out_size, void* d_ws, size_t ws_size,
                              hipStream_t stream)
{
    const int*   z     = (const int*)  d_in[0];
    const float* pos   = (const float*)d_in[1];
    const int*   ei    = (const int*)  d_in[2];
    const float* shift = (const float*)d_in[3];
    const float* emb = (const float*)d_in[6];
    const float* rw1 = (const float*)d_in[7];
    const float* rb1 = (const float*)d_in[8];
    const float* rw2 = (const float*)d_in[9];
    const float* rb2 = (const float*)d_in[10];
    const float* wp0 = (const float*)d_in[11];
    const float* wp1 = (const float*)d_in[12];
    const float* wp2 = (const float*)d_in[13];
    const float* s0  = (const float*)d_in[14];
    const float* s1  = (const float*)d_in[15];
    const float* s2  = (const float*)d_in[16];
    const float* wq  = (const float*)d_in[17];
    const float* wk  = (const float*)d_in[18];
    const float* wv  = (const float*)d_in[19];
    const float* m1  = (const float*)d_in[20];
    const float* mb1 = (const float*)d_in[21];
    const float* m2  = (const float*)d_in[22];
    const float* mb2 = (const float*)d_in[23];

    float* ws = (float*)d_ws;
    size_t off = 0;
    int4*  edata = (int4*)(ws + off); off += (size_t)4*EE;
    int*   deg    = (int*)(ws + off); off += NN;
    int*   startA = (int*)(ws + off); off += NN + 4;
    int*   cursor = (int*)(ws + off); off += NN;
    int*   bsum   = (int*)(ws + off); off += 256;
    float* hT  = ws + off; off += (size_t)240*NNP;
    float* acc = ws + off; off += (size_t)NNP*240;
    unsigned* Pa = (unsigned*)(ws + off); off += (size_t)NNP*64;
    unsigned* Pb = (unsigned*)(ws + off); off += (size_t)NNP*64;
    uint2* tabpack = (uint2*)(ws + off); off += (size_t)4*NB*64*2;
    float* wpc = ws + off; off += 4*64*112;
    float* pt  = ws + off; off += 100*112;
    float* s0T = ws + off; off += 4*4096;
    float* s1T = ws + off; off += 4*1024;
    float* s2T = ws + off; off += 4*256;
    float* wpcT = ws + off; off += 4*7168;
    float* kq  = ws + off; off += BB*64;
    float* zr  = ws + off; off += BB*176;
    float* rfall = acc;    // overlay: rfall consumed by pack_tab before agg writes acc

    prep_w<<<(4*64*112 + 255)/256, 256, 0, stream>>>(wp0, wp1, wp2, wpc);
    prep_wT<<<(4*7168 + 255)/256, 256, 0, stream>>>(s0, s1, s2, wpc, s0T, s1T, s2T, wpcT);
    prep_pt<<<100, 128, 0, stream>>>(emb, wpc, pt);

    hipMemsetAsync(deg, 0, NN*sizeof(int), stream);
    hist_kernel<<<(EE + 255)/256, 256, 0, stream>>>(ei, deg);
    const int NSB = (NN + 255)/256;
    scan1<<<NSB, 256, 0, stream>>>(deg, startA, bsum);
    scan2<<<1, 256, 0, stream>>>(bsum, NSB);
    scan3<<<NSB, 256, 0, stream>>>(startA, bsum, cursor);
    geom_scatter<<<(EE + 255)/256, 256, 0, stream>>>(pos, ei, shift, cursor, edata);

    build_rf<<<4*(NB+1), 128, 0, stream>>>(rw1, rb1, rw2, rb2, rfall);
    pack_tab<<<(4*NB*64 + 255)/256, 256, 0, stream>>>(rfall, tabpack);
    init_hT<<<NNP/64, 256, 0, stream>>>(z, emb, hT);
    init_P<<<NN, 64, 0, stream>>>(z, pt, Pa);

    unsigned* Pcur = Pa; unsigned* Pnxt = Pb;
    for (int L = 0; L < 4; L++) {
        int hasNext = (L < 3) ? 1 : 0;
        agg_kernel<<<NN/(WPB*2), 256, 0, stream>>>(
            Pcur, edata, startA, tabpack + (size_t)L*NB*64, acc);
        update_kernel<<<NNP/64, 256, 0, stream>>>(
            hT, acc, s0T + L*4096, s1T + L*1024, s2T + L*256,
            wpcT + (hasNext ? (L+1)*7168 : 0), Pnxt, hasNext);
        unsigned* tmp = Pcur; Pcur = Pnxt; Pnxt = tmp;
    }

    readout_a<<<BB, 64, 0, stream>>>(hT, wq, wk, kq, zr);
    readout_b<<<BB, 64, 0, stream>>>(hT, kq, wv, zr);
    readout_c<<<BB, 128, 0, stream>>>(zr, m1, mb1, m2, mb2, (float*)d_out);
}

// Round 15
// 788.748 us; speedup vs baseline: 1.4555x; 1.4555x over previous
//
#include <hip/hip_runtime.h>
#include <hip/hip_bf16.h>
#include <hip/hip_fp16.h>

#define NN 50000
#define NNP 50048          // padded node count (782 * 64)
#define EE 800000
#define BB 1000
#define NB 2048            // radial table bins over [0, RTMAX]
#define RTMAX 10.0f
#define WPB 4              // waves per block in agg; each wave owns 2 nodes

typedef _Float16 half8 __attribute__((ext_vector_type(8)));
typedef float floatx4 __attribute__((ext_vector_type(4)));

__device__ __forceinline__ float silu(float x){ return x / (1.0f + __expf(-x)); }

// Internal channel layout (permuted vs reference):
//   scalar: ch j          = j            (j<64)
//   vector: ch 64+32d+j   = v[j][d]      (j<32, d<3)
//   tensor: ch 160+16e+j  = t[j][e]      (j<16, e<5)
// h stored f32 [NNP][256]; channels 240..255 stay zero (K-pad for MFMA).

// ---------------- combined projection weights: wpc[L][k][112] ----------------
__global__ __launch_bounds__(256) void prep_w(
    const float* __restrict__ wp0, const float* __restrict__ wp1, const float* __restrict__ wp2,
    float* __restrict__ wpc)
{
    int t = blockIdx.x * 256 + threadIdx.x;
    if (t >= 4*64*112) return;
    int L = t / (64*112); int r = t % (64*112); int k = r / 112; int j = r % 112;
    float w;
    if (j < 64)      w = wp0[L*64*64 + k*64 + j];
    else if (j < 96) w = wp1[L*64*32 + k*32 + (j-64)];
    else             w = wp2[L*64*16 + k*16 + (j-96)];
    wpc[t] = w;
}

// padded transposed weights for MFMA B-frags:
// s0Tp[L][64][72], s1Tp[L][32][40], s2Tp[L][16][40], wpTp[L][112][72] (pads zero)
__global__ __launch_bounds__(256) void prep_wT(
    const float* __restrict__ s0, const float* __restrict__ s1, const float* __restrict__ s2,
    const float* __restrict__ wpc,
    float* __restrict__ s0Tp, float* __restrict__ s1Tp, float* __restrict__ s2Tp,
    float* __restrict__ wpTp)
{
    int t = blockIdx.x*256 + threadIdx.x;
    if (t < 4*64*72) {
        int L = t / 4608; int r = t % 4608; int j = r / 72; int k = r % 72;
        s0Tp[t] = (k < 64) ? s0[L*4096 + k*64 + j] : 0.0f;
    }
    if (t < 4*32*40) {
        int L = t / 1280; int r = t % 1280; int j = r / 40; int k = r % 40;
        s1Tp[t] = (k < 32) ? s1[L*1024 + k*32 + j] : 0.0f;
    }
    if (t < 4*16*40) {
        int L = t / 640; int r = t % 640; int j = r / 40; int k = r % 40;
        s2Tp[t] = (k < 16) ? s2[L*256 + k*16 + j] : 0.0f;
    }
    if (t < 4*112*72) {
        int L = t / 8064; int r = t % 8064; int m = r / 72; int k = r % 72;
        wpTp[t] = (k < 64) ? wpc[L*7168 + k*112 + m] : 0.0f;
    }
}

// prodTable[z][j] = sum_k emb[z][k] * wpc_L0[k][j]
__global__ __launch_bounds__(128) void prep_pt(
    const float* __restrict__ emb, const float* __restrict__ wpc, float* __restrict__ pt)
{
    int zz = blockIdx.x; int j = threadIdx.x;
    __shared__ float er[64];
    if (j < 64) er[j] = emb[zz*64 + j];
    __syncthreads();
    if (j >= 112) return;
    float s = 0.0f;
    #pragma unroll
    for (int k = 0; k < 64; k++) s += er[k] * wpc[k*112 + j];
    pt[zz*112 + j] = s;
}

// ---------------- CSR build ----------------
__global__ __launch_bounds__(256) void hist_kernel(const int* __restrict__ ei, int* __restrict__ deg)
{
    int e = blockIdx.x * 256 + threadIdx.x;
    if (e < EE) atomicAdd(&deg[ei[EE + e]], 1);
}

__global__ __launch_bounds__(256) void scan1(const int* __restrict__ deg,
                                             int* __restrict__ start, int* __restrict__ bsum)
{
    __shared__ int buf[256];
    int tid = threadIdx.x;
    int i = blockIdx.x*256 + tid;
    int v = (i < NN) ? deg[i] : 0;
    buf[tid] = v; __syncthreads();
    #pragma unroll
    for (int off = 1; off < 256; off <<= 1) {
        int t = (tid >= off) ? buf[tid-off] : 0;
        __syncthreads(); buf[tid] += t; __syncthreads();
    }
    if (i < NN) start[i] = buf[tid] - v;
    if (tid == 255) bsum[blockIdx.x] = buf[255];
}
__global__ __launch_bounds__(256) void scan2(int* __restrict__ bsum, int nb)
{
    __shared__ int buf[256];
    int tid = threadIdx.x;
    int v = (tid < nb) ? bsum[tid] : 0;
    buf[tid] = v; __syncthreads();
    #pragma unroll
    for (int off = 1; off < 256; off <<= 1) {
        int t = (tid >= off) ? buf[tid-off] : 0;
        __syncthreads(); buf[tid] += t; __syncthreads();
    }
    if (tid < nb) bsum[tid] = buf[tid] - v;
}
__global__ __launch_bounds__(256) void scan3(int* __restrict__ start, const int* __restrict__ bsum,
                                             int* __restrict__ cursor)
{
    int i = blockIdx.x*256 + threadIdx.x;
    if (i < NN) { int v = start[i] + bsum[blockIdx.x]; start[i] = v; cursor[i] = v; }
    if (i == 0) start[NN] = EE;
}

// ---------------- fused geometry + scatter: 16B packed edge record ----------------
__global__ __launch_bounds__(256) void geom_scatter(
    const float* __restrict__ pos, const int* __restrict__ ei, const float* __restrict__ shift,
    int* __restrict__ cursor, int4* __restrict__ edata)
{
    int e = blockIdx.x * 256 + threadIdx.x;
    if (e >= EE) return;
    int s = ei[e], d = ei[EE + e];
    float vx = pos[d*3+0] - pos[s*3+0] + shift[e*3+0];
    float vy = pos[d*3+1] - pos[s*3+1] + shift[e*3+1];
    float vz = pos[d*3+2] - pos[s*3+2] + shift[e*3+2];
    float r = sqrtf(vx*vx + vy*vy + vz*vz);
    float inv = 1.0f / (r + 1e-9f);
    float x = vx*inv, y = vy*inv, z = vz*inv;
    int p = atomicAdd(&cursor[d], 1);
    __half2 xy = __floats2half2_rn(x, y);
    __half2 z0 = __floats2half2_rn(z, 0.0f);
    int4 rec;
    rec.x = s;
    rec.y = __float_as_int(r);
    rec.z = *(const int*)&xy;
    rec.w = *(const int*)&z0;
    edata[p] = rec;
}

// ---------------- radial features on the bin grid (f32, NB+1 bins) ----------------
__global__ __launch_bounds__(128) void build_rf(
    const float* __restrict__ rw1, const float* __restrict__ rb1,
    const float* __restrict__ rw2, const float* __restrict__ rb2,
    float* __restrict__ rfall)
{
    int idx = blockIdx.x;
    int L = idx / (NB+1), bin = idx % (NB+1);
    float r = bin * (RTMAX / NB);
    int t = threadIdx.x;
    __shared__ float h1[64];
    if (t < 64) {
        float s = rb1[L*64 + t];
        #pragma unroll
        for (int i = 0; i < 10; i++) { float a = 1.8f*r - (float)i; s += __expf(-a*a) * rw1[L*640 + i*64 + t]; }
        h1[t] = silu(s);
    }
    __syncthreads();
    if (t < 112) {
        float s = rb2[L*112 + t];
        #pragma unroll 8
        for (int k = 0; k < 64; k++) s += h1[k] * rw2[(size_t)L*7168 + k*112 + t];
        rfall[(size_t)idx*112 + t] = s * 0.25f;
    }
}

// pack: tabpack[L][bin][lane] = 8B { half2(A_lo,A_hi), half2(B_lo,B_hi) }
__global__ __launch_bounds__(256) void pack_tab(
    const float* __restrict__ rfall, uint2* __restrict__ tabpack)
{
    int t = blockIdx.x*256 + threadIdx.x;
    if (t >= 4*NB*64) return;
    int lane = t & 63;
    int rest = t >> 6;
    int L = rest / NB, bin = rest % NB;
    const float* lo = rfall + (size_t)(L*(NB+1) + bin)*112;
    const float* hi = lo + 112;
    float aLo = lo[lane], aHi = hi[lane];
    float bLo = (lane < 48) ? lo[64+lane] : 0.0f;
    float bHi = (lane < 48) ? hi[64+lane] : 0.0f;
    __half2 ha = __floats2half2_rn(aLo, aHi);
    __half2 hb = __floats2half2_rn(bLo, bHi);
    uint2 o;
    o.x = *(const unsigned*)&ha;
    o.y = *(const unsigned*)&hb;
    tabpack[t] = o;
}

// ---------------- init: h f32 [NNP][256] and packed P0 ----------------
__global__ __launch_bounds__(256) void init_h32(
    const int* __restrict__ z, const float* __restrict__ emb, float* __restrict__ hG)
{
    int n = blockIdx.x; int j = threadIdx.x;
    int zz = z[n];
    hG[(size_t)n*256 + j] = (j < 64) ? emb[zz*64 + j] : 0.0f;
}

__global__ __launch_bounds__(64) void init_P(
    const int* __restrict__ z, const float* __restrict__ pt, unsigned* __restrict__ Ppack)
{
    int n = blockIdx.x; int j = threadIdx.x;
    int zz = z[n];
    float a = pt[zz*112 + j];
    float b = (j < 48) ? pt[zz*112 + 64 + j] : 0.0f;
    __half2 hp = __floats2half2_rn(a, b);
    Ppack[(size_t)n*64 + j] = *(const unsigned*)&hp;
}

// ---------------- aggregation: 2 nodes per wave -> acc rows (permuted layout) ----------------
__global__ __launch_bounds__(256) void agg_kernel(
    const unsigned* __restrict__ Ppack, const int4* __restrict__ edata,
    const int* __restrict__ start, const uint2* __restrict__ tabp,
    float* __restrict__ acc)
{
    int lane = threadIdx.x & 63;
    int wv   = threadIdx.x >> 6;
    int nA = blockIdx.x*(WPB*2) + wv*2;
    int nB = nA + 1;

    __shared__ float ebuf_s[WPB][2][16*12];
    __shared__ float accb_s[WPB][2][240];

    int p0A = start[nA], p1A = start[nA+1];
    int p1B = start[nB+1];
    float aS_A = 0.0f, aS_B = 0.0f;
    float aB_A[5] = {0,0,0,0,0};
    float aB_B[5] = {0,0,0,0,0};
    bool hasB = lane < 48;
    int sbase = (lane < 32) ? 0 : 3;
    int ncomp = (lane < 32) ? 3 : 5;
    const float binscale = (float)NB / RTMAX;
    const float C3 = 1.7320508075688772f, C15 = 3.872983346207417f, C5 = 2.23606797749979f;

    const char* tabc = (const char*)tabp;
    const char* Pc   = (const char*)Ppack;

    int baseA = p0A, baseB = p1A;
    while (baseA < p1A || baseB < p1B) {
        int cntA = p1A - baseA; cntA = cntA < 0 ? 0 : (cntA > 16 ? 16 : cntA);
        int cntB = p1B - baseB; cntB = cntB < 0 ? 0 : (cntB > 16 ? 16 : cntB);
        #pragma unroll
        for (int s = 0; s < 2; s++) {
            int cnt  = s ? cntB : cntA;
            int base = s ? baseB : baseA;
            if (lane < cnt) {
                int4 rec = edata[base + lane];
                float f = fminf(__int_as_float(rec.y) * binscale, (float)NB - 0.5f);
                int b = (int)f;
                float fr = f - (float)b;
                __half2 xy = *(const __half2*)&rec.z;
                __half2 z0 = *(const __half2*)&rec.w;
                float x = __half2float(xy.x), y = __half2float(xy.y), z = __half2float(z0.x);
                float4* v4 = (float4*)(ebuf_s[wv][s] + lane*12);
                v4[0] = make_float4(__int_as_float(b*512), __int_as_float(rec.x*256), fr, 0.0f);
                v4[1] = make_float4(C3*x, C3*y, C3*z, C15*x*y);
                v4[2] = make_float4(C15*y*z, 0.5f*C5*(3.0f*z*z - 1.0f), C15*x*z, 0.5f*C15*(x*x - y*y));
            }
        }
        asm volatile("s_waitcnt lgkmcnt(0)" ::: "memory");
        #pragma unroll
        for (int s = 0; s < 2; s++) {
            int cnt = s ? cntB : cntA;
            const float* eb = ebuf_s[wv][s];
            float aS_l = 0.0f;
            float aB_l[5] = {0,0,0,0,0};
            #pragma unroll 4
            for (int e = 0; e < 16; e++) {
                if (e < cnt) {
                    const float* ep = eb + e*12;
                    int boff = __float_as_int(ep[0]);
                    int poff = __float_as_int(ep[1]);
                    float fr = ep[2];
                    uint2 tt = *(const uint2*)(tabc + boff + lane*8);
                    unsigned pv = *(const unsigned*)(Pc + poff + lane*4);
                    __half2 ha = *(const __half2*)&tt.x;
                    __half2 hp = *(const __half2*)&pv;
                    float alo = __half2float(ha.x), ahi = __half2float(ha.y);
                    float pA  = __half2float(hp.x);
                    aS_l += (alo + (ahi - alo)*fr) * pA;
                    if (hasB) {
                        __half2 hb = *(const __half2*)&tt.y;
                        float blo = __half2float(hb.x), bhi = __half2float(hb.y);
                        float pB  = __half2float(hp.y);
                        float msg = (blo + (bhi - blo)*fr) * pB;
                        #pragma unroll
                        for (int d = 0; d < 5; d++)
                            if (d < ncomp) aB_l[d] += msg * ep[4 + sbase + d];
                    }
                }
            }
            if (s == 0) {
                aS_A += aS_l;
                #pragma unroll
                for (int d = 0; d < 5; d++) aB_A[d] += aB_l[d];
            } else {
                aS_B += aS_l;
                #pragma unroll
                for (int d = 0; d < 5; d++) aB_B[d] += aB_l[d];
            }
        }
        asm volatile("s_waitcnt lgkmcnt(0)" ::: "memory");
        baseA += 16; baseB += 16;
    }

    // stage into LDS in PERMUTED channel layout
    #pragma unroll
    for (int s = 0; s < 2; s++) {
        float* ab = accb_s[wv][s];
        ab[lane] = s ? aS_B : aS_A;
        const float* aB = s ? aB_B : aB_A;
        if (lane < 32) {
            #pragma unroll
            for (int d = 0; d < 3; d++) ab[64 + 32*d + lane] = aB[d];
        } else if (lane < 48) {
            #pragma unroll
            for (int d = 0; d < 5; d++) ab[160 + 16*d + (lane-32)] = aB[d];
        }
    }
    asm volatile("s_waitcnt lgkmcnt(0)" ::: "memory");
    #pragma unroll
    for (int s = 0; s < 2; s++) {
        float* arow = acc + (size_t)(nA + s)*240;
        const float* ab = accb_s[wv][s];
        #pragma unroll
        for (int c = lane; c < 240; c += 64) arow[c] = ab[c];
    }
}

// ---------------- MFMA node update + projection (h stays f32) ----------------
// block = 256 = 4 waves; wave = 16 nodes. Weights f16 in LDS; A-frags cvt'd
// from f32 h at load; acc = MFMA C operand; D stored f32 straight to hG.
__global__ __launch_bounds__(256) void update_kernel(
    float* __restrict__ hG, const float* __restrict__ acc,
    const float* __restrict__ s0Tp, const float* __restrict__ s1Tp, const float* __restrict__ s2Tp,
    const float* __restrict__ wpTp, unsigned* __restrict__ Pnext, int hasNext)
{
    __shared__ _Float16 w0[64*72];     // 9216 B
    __shared__ _Float16 w1[32*40];     // 2560 B
    __shared__ _Float16 w2[16*40];     // 1280 B
    __shared__ _Float16 wpl[112*72];   // 16128 B
    __shared__ _Float16 sn[64*72];     // 9216 B  (s_new f16, row stride 72)
    __shared__ _Float16 pbuf[64*120];  // 15360 B (P result, row stride 120)

    int tid = threadIdx.x;
    int lane = tid & 63, wv = tid >> 6;
    int m = lane & 15, quad = lane >> 4;
    int nblk0 = blockIdx.x * 64;
    int n0 = nblk0 + wv*16;

    for (int i = tid; i < 64*72; i += 256) w0[i] = (_Float16)s0Tp[i];
    for (int i = tid; i < 32*40; i += 256) w1[i] = (_Float16)s1Tp[i];
    for (int i = tid; i < 16*40; i += 256) w2[i] = (_Float16)s2Tp[i];
    for (int i = tid; i < 112*72; i += 256) wpl[i] = (_Float16)wpTp[i];
    __syncthreads();

    size_t hrowm = (size_t)(n0 + m)*256;
    size_t arow0 = (size_t)(n0 + quad*4)*240;
    size_t orow0 = (size_t)(n0 + quad*4)*256;

    // load 8 consecutive f32 h channels -> half8
#define LD8(OFF) ({ \
        float4 v0_ = *(const float4*)(hG + (OFF)); \
        float4 v1_ = *(const float4*)(hG + (OFF) + 4); \
        half8 h_; \
        h_[0] = (_Float16)v0_.x; h_[1] = (_Float16)v0_.y; \
        h_[2] = (_Float16)v0_.z; h_[3] = (_Float16)v0_.w; \
        h_[4] = (_Float16)v1_.x; h_[5] = (_Float16)v1_.y; \
        h_[6] = (_Float16)v1_.z; h_[7] = (_Float16)v1_.w; h_; })

    // ---- GEMM0: scalar block (cols 0..63, K 0..63) ----
    {
        half8 a0 = LD8(hrowm + 0  + quad*8);
        half8 a1 = LD8(hrowm + 32 + quad*8);
        #pragma unroll
        for (int t = 0; t < 4; t++) {
            int cb = 16*t;
            floatx4 c;
            #pragma unroll
            for (int r = 0; r < 4; r++) c[r] = acc[arow0 + (size_t)r*240 + cb + m];
            c = __builtin_amdgcn_mfma_f32_16x16x32_f16(a0, *(const half8*)&w0[(cb+m)*72 + 0  + quad*8], c, 0, 0, 0);
            c = __builtin_amdgcn_mfma_f32_16x16x32_f16(a1, *(const half8*)&w0[(cb+m)*72 + 32 + quad*8], c, 0, 0, 0);
            #pragma unroll
            for (int r = 0; r < 4; r++) {
                float u = silu(c[r]);
                hG[orow0 + (size_t)r*256 + cb + m] = u;
                sn[(wv*16 + quad*4 + r)*72 + cb + m] = (_Float16)u;
            }
        }
    }
    // ---- GEMM1: vector blocks d=0..2 (cols 64+32d.., K=32) ----
    #pragma unroll
    for (int d = 0; d < 3; d++) {
        int kb = 64 + 32*d;
        half8 av = LD8(hrowm + kb + quad*8);
        #pragma unroll
        for (int t = 0; t < 2; t++) {
            int cb = kb + 16*t;
            floatx4 c;
            #pragma unroll
            for (int r = 0; r < 4; r++) c[r] = acc[arow0 + (size_t)r*240 + cb + m];
            c = __builtin_amdgcn_mfma_f32_16x16x32_f16(av, *(const half8*)&w1[(16*t+m)*40 + quad*8], c, 0, 0, 0);
            #pragma unroll
            for (int r = 0; r < 4; r++) hG[orow0 + (size_t)r*256 + cb + m] = c[r];
        }
    }
    // ---- GEMM2: tensor blocks e=0..4 (cols 160+16e.., K=16 zero-padded; A reads
    //      next block's channels / zero channels 240..255 against zero weights) ----
    #pragma unroll
    for (int e = 0; e < 5; e++) {
        int kb = 160 + 16*e;
        half8 at_ = LD8(hrowm + kb + quad*8);
        floatx4 c;
        #pragma unroll
        for (int r = 0; r < 4; r++) c[r] = acc[arow0 + (size_t)r*240 + kb + m];
        c = __builtin_amdgcn_mfma_f32_16x16x32_f16(at_, *(const half8*)&w2[m*40 + quad*8], c, 0, 0, 0);
        #pragma unroll
        for (int r = 0; r < 4; r++) hG[orow0 + (size_t)r*256 + kb + m] = c[r];
    }

    // ---- projection P = silu(s_new) @ wpc_next (A from own-wave sn rows) ----
    if (hasNext) {
        asm volatile("s_waitcnt lgkmcnt(0)" ::: "memory");   // sn writes visible to own wave
        half8 p0 = *(const half8*)&sn[(wv*16 + m)*72 + 0  + quad*8];
        half8 p1 = *(const half8*)&sn[(wv*16 + m)*72 + 32 + quad*8];
        #pragma unroll
        for (int t = 0; t < 7; t++) {
            floatx4 c = {0.0f, 0.0f, 0.0f, 0.0f};
            c = __builtin_amdgcn_mfma_f32_16x16x32_f16(p0, *(const half8*)&wpl[(16*t+m)*72 + 0  + quad*8], c, 0, 0, 0);
            c = __builtin_amdgcn_mfma_f32_16x16x32_f16(p1, *(const half8*)&wpl[(16*t+m)*72 + 32 + quad*8], c, 0, 0, 0);
            #pragma unroll
            for (int r = 0; r < 4; r++) pbuf[(wv*16 + quad*4 + r)*120 + 16*t + m] = (_Float16)c[r];
        }
        __syncthreads();
        for (int i = tid; i < 64*64; i += 256) {
            int node = i >> 6, j = i & 63;
            _Float16 aa = pbuf[node*120 + j];
            _Float16 bb = (j < 48) ? pbuf[node*120 + 64 + j] : (_Float16)0.0f;
            unsigned lo = *(const unsigned short*)&aa;
            unsigned hi = *(const unsigned short*)&bb;
            if (nblk0 + node < NN) Pnext[(size_t)(nblk0 + node)*64 + j] = lo | (hi << 16);
        }
    }
#undef LD8
}

// ---------------- readout A (f32 h, permuted layout) ----------------
__global__ __launch_bounds__(64) void readout_a(
    const float* __restrict__ hG, const float* __restrict__ wq, const float* __restrict__ wk,
    float* __restrict__ kq, float* __restrict__ zr)
{
    int b = blockIdx.x; int j = threadIdx.x;
    int na = 50 * b;
    const float* hr = hG + (size_t)na*256;
    __shared__ float sa[64], qv[64];
    sa[j] = hr[j];
    __syncthreads();
    float q = 0.0f;
    #pragma unroll 8
    for (int k = 0; k < 64; k++) q += sa[k] * wq[k*64 + j];
    qv[j] = q;
    zr[b*176 + j] = sa[j];
    if (j < 32) {
        float nv = 0.0f;
        #pragma unroll
        for (int c = 0; c < 3; c++) { float v = hr[64 + 32*c + j]; nv += v*v; }
        zr[b*176 + 128 + j] = nv;
    }
    if (j < 16) {
        float nt = 0.0f;
        #pragma unroll
        for (int c = 0; c < 5; c++) { float v = hr[160 + 16*c + j]; nt += v*v; }
        zr[b*176 + 160 + j] = nt;
    }
    __syncthreads();
    float s = 0.0f;
    #pragma unroll 8
    for (int jj = 0; jj < 64; jj++) s += wk[j*64 + jj] * qv[jj];
    kq[b*64 + j] = s;
}

// ---------------- readout B ----------------
__global__ __launch_bounds__(64) void readout_b(
    const float* __restrict__ hG, const float* __restrict__ kq, const float* __restrict__ wv,
    float* __restrict__ zr)
{
    int b = blockIdx.x; int lane = threadIdx.x;
    __shared__ float hblk[64][51];
    __shared__ float at[64], hbar[64];
    if (lane < 50) {
        const float* hr = hG + (size_t)(50*b + lane)*256;
        #pragma unroll 8
        for (int k = 0; k < 64; k++) hblk[k][lane] = hr[k];
    }
    __syncthreads();
    const float* kqb = kq + b*64;
    float logit = -1e30f;
    if (lane < 50) {
        float t = 0.0f;
        #pragma unroll 8
        for (int k = 0; k < 64; k++) t += hblk[k][lane] * kqb[k];
        logit = t * 0.125f;
    }
    float mx = logit;
    for (int o = 32; o; o >>= 1) mx = fmaxf(mx, __shfl_xor(mx, o));
    float ex = (lane < 50) ? __expf(logit - mx) : 0.0f;
    float den = ex;
    for (int o = 32; o; o >>= 1) den += __shfl_xor(den, o);
    at[lane] = ex / den;
    __syncthreads();
    float hb = 0.0f;
    #pragma unroll 1
    for (int i = 0; i < 50; i++) hb += at[i] * hblk[lane][i];
    hbar[lane] = hb;
    __syncthreads();
    float c = 0.0f;
    #pragma unroll 8
    for (int k = 0; k < 64; k++) c += hbar[k] * wv[k*64 + lane];
    zr[b*176 + 64 + lane] = c;
}

// ---------------- readout C ----------------
__global__ __launch_bounds__(128) void readout_c(
    const float* __restrict__ zr, const float* __restrict__ m1, const float* __restrict__ mb1,
    const float* __restrict__ m2, const float* __restrict__ mb2, float* __restrict__ out)
{
    int b = blockIdx.x; int j = threadIdx.x;
    __shared__ float z[176], tb[128];
    for (int t = j; t < 176; t += 128) z[t] = zr[b*176 + t];
    __syncthreads();
    float a = mb1[j];
    #pragma unroll 8
    for (int k = 0; k < 176; k++) a += z[k] * m1[k*128 + j];
    tb[j] = silu(a);
    __syncthreads();
    float o = mb2[j];
    #pragma unroll 8
    for (int k = 0; k < 128; k++) o += tb[k] * m2[k*128 + j];
    out[b*128 + j] = o;
}

extern "C" void kernel_launch(void* const* d_in, const int* in_sizes, int n_in,
                              void* d_out, int out_size, void* d_ws, size_t ws_size,
                              hipStream_t stream)
{
    const int*   z     = (const int*)  d_in[0];
    const float* pos   = (const float*)d_in[1];
    const int*   ei    = (const int*)  d_in[2];
    const float* shift = (const float*)d_in[3];
    const float* emb = (const float*)d_in[6];
    const float* rw1 = (const float*)d_in[7];
    const float* rb1 = (const float*)d_in[8];
    const float* rw2 = (const float*)d_in[9];
    const float* rb2 = (const float*)d_in[10];
    const float* wp0 = (const float*)d_in[11];
    const float* wp1 = (const float*)d_in[12];
    const float* wp2 = (const float*)d_in[13];
    const float* s0  = (const float*)d_in[14];
    const float* s1  = (const float*)d_in[15];
    const float* s2  = (const float*)d_in[16];
    const float* wq  = (const float*)d_in[17];
    const float* wk  = (const float*)d_in[18];
    const float* wv  = (const float*)d_in[19];
    const float* m1  = (const float*)d_in[20];
    const float* mb1 = (const float*)d_in[21];
    const float* m2  = (const float*)d_in[22];
    const float* mb2 = (const float*)d_in[23];

    float* ws = (float*)d_ws;
    size_t off = 0;
    int4*  edata = (int4*)(ws + off); off += (size_t)4*EE;
    int*   deg    = (int*)(ws + off); off += NN;
    int*   startA = (int*)(ws + off); off += NN + 4;
    int*   cursor = (int*)(ws + off); off += NN;
    int*   bsum   = (int*)(ws + off); off += 256;
    float* hG  = ws + off; off += (size_t)NNP*256;   // f32 [NNP][256]
    float* acc = ws + off; off += (size_t)NNP*240;
    unsigned* Pa = (unsigned*)(ws + off); off += (size_t)NNP*64;
    unsigned* Pb = (unsigned*)(ws + off); off += (size_t)NNP*64;
    uint2* tabpack = (uint2*)(ws + off); off += (size_t)4*NB*64*2;
    float* wpc = ws + off; off += 4*64*112;
    float* pt  = ws + off; off += 100*112;
    float* s0Tp = ws + off; off += 4*4608;
    float* s1Tp = ws + off; off += 4*1280;
    float* s2Tp = ws + off; off += 4*640;
    float* wpTp = ws + off; off += 4*8064;
    float* kq  = ws + off; off += BB*64;
    float* zr  = ws + off; off += BB*176;
    float* rfall = acc;    // overlay: rfall consumed by pack_tab before agg writes acc

    prep_w<<<(4*64*112 + 255)/256, 256, 0, stream>>>(wp0, wp1, wp2, wpc);
    prep_wT<<<(4*8064 + 255)/256, 256, 0, stream>>>(s0, s1, s2, wpc, s0Tp, s1Tp, s2Tp, wpTp);
    prep_pt<<<100, 128, 0, stream>>>(emb, wpc, pt);

    hipMemsetAsync(deg, 0, NN*sizeof(int), stream);
    hist_kernel<<<(EE + 255)/256, 256, 0, stream>>>(ei, deg);
    const int NSB = (NN + 255)/256;
    scan1<<<NSB, 256, 0, stream>>>(deg, startA, bsum);
    scan2<<<1, 256, 0, stream>>>(bsum, NSB);
    scan3<<<NSB, 256, 0, stream>>>(startA, bsum, cursor);
    geom_scatter<<<(EE + 255)/256, 256, 0, stream>>>(pos, ei, shift, cursor, edata);

    build_rf<<<4*(NB+1), 128, 0, stream>>>(rw1, rb1, rw2, rb2, rfall);
    pack_tab<<<(4*NB*64 + 255)/256, 256, 0, stream>>>(rfall, tabpack);
    init_h32<<<NN, 256, 0, stream>>>(z, emb, hG);
    init_P<<<NN, 64, 0, stream>>>(z, pt, Pa);

    unsigned* Pcur = Pa; unsigned* Pnxt = Pb;
    for (int L = 0; L < 4; L++) {
        int hasNext = (L < 3) ? 1 : 0;
        agg_kernel<<<NN/(WPB*2), 256, 0, stream>>>(
            Pcur, edata, startA, tabpack + (size_t)L*NB*64, acc);
        update_kernel<<<NNP/64, 256, 0, stream>>>(
            hG, acc, s0Tp + L*4608, s1Tp + L*1280, s2Tp + L*640,
            wpTp + (hasNext ? (L+1)*8064 : 0), Pnxt, hasNext);
        unsigned* tmp = Pcur; Pcur = Pnxt; Pnxt = tmp;
    }

    readout_a<<<BB, 64, 0, stream>>>(hG, wq, wk, kq, zr);
    readout_b<<<BB, 64, 0, stream>>>(hG, kq, wv, zr);
    readout_c<<<BB, 128, 0, stream>>>(zr, m1, mb1, m2, mb2, (float*)d_out);
}

// Round 16
// 762.950 us; speedup vs baseline: 1.5047x; 1.0338x over previous
//
#include <hip/hip_runtime.h>
#include <hip/hip_bf16.h>
#include <hip/hip_fp16.h>

#define NN 50000
#define NNP 50048          // padded node count (782 * 64)
#define EE 800000
#define BB 1000
#define NB 2048            // radial table bins over [0, RTMAX]
#define RTMAX 10.0f
#define WPB 4              // waves per block in agg; each wave owns 2 nodes

typedef _Float16 half8 __attribute__((ext_vector_type(8)));
typedef float floatx4 __attribute__((ext_vector_type(4)));

__device__ __forceinline__ float silu(float x){ return x / (1.0f + __expf(-x)); }

// Internal channel layout (permuted vs reference):
//   scalar: ch j          = j            (j<64)
//   vector: ch 64+32d+j   = v[j][d]      (j<32, d<3)
//   tensor: ch 160+16e+j  = t[j][e]      (j<16, e<5)
// h stored f32 [NNP][256]; channels 240..255 stay zero (K-pad for MFMA).

// ---------------- prep_a: zero deg + wpc + s*Tp (no wpc dependency) ----------------
__global__ __launch_bounds__(256) void prep_a(
    const float* __restrict__ wp0, const float* __restrict__ wp1, const float* __restrict__ wp2,
    const float* __restrict__ s0, const float* __restrict__ s1, const float* __restrict__ s2,
    float* __restrict__ wpc, float* __restrict__ s0Tp, float* __restrict__ s1Tp,
    float* __restrict__ s2Tp, int* __restrict__ deg)
{
    int t = blockIdx.x * 256 + threadIdx.x;
    if (t < NN) deg[t] = 0;
    if (t < 4*64*112) {
        int L = t / (64*112); int r = t % (64*112); int k = r / 112; int j = r % 112;
        float w;
        if (j < 64)      w = wp0[L*64*64 + k*64 + j];
        else if (j < 96) w = wp1[L*64*32 + k*32 + (j-64)];
        else             w = wp2[L*64*16 + k*16 + (j-96)];
        wpc[t] = w;
    }
    if (t < 4*64*72) {
        int L = t / 4608; int r = t % 4608; int j = r / 72; int k = r % 72;
        s0Tp[t] = (k < 64) ? s0[L*4096 + k*64 + j] : 0.0f;
    }
    if (t < 4*32*40) {
        int L = t / 1280; int r = t % 1280; int j = r / 40; int k = r % 40;
        s1Tp[t] = (k < 32) ? s1[L*1024 + k*32 + j] : 0.0f;
    }
    if (t < 4*16*40) {
        int L = t / 640; int r = t % 640; int j = r / 40; int k = r % 40;
        s2Tp[t] = (k < 16) ? s2[L*256 + k*16 + j] : 0.0f;
    }
}

// ---------------- prep_b: wpTp + pt (need wpc) ----------------
__global__ __launch_bounds__(256) void prep_b(
    const float* __restrict__ wpc, const float* __restrict__ emb,
    float* __restrict__ wpTp, float* __restrict__ pt)
{
    int t = blockIdx.x*256 + threadIdx.x;
    if (t < 4*112*72) {
        int L = t / 8064; int r = t % 8064; int m = r / 72; int k = r % 72;
        wpTp[t] = (k < 64) ? wpc[L*7168 + k*112 + m] : 0.0f;
    }
    if (t < 100*112) {
        int zz = t / 112, j = t % 112;
        float s = 0.0f;
        #pragma unroll 8
        for (int k = 0; k < 64; k++) s += emb[zz*64 + k] * wpc[k*112 + j];
        pt[t] = s;
    }
}

// ---------------- CSR build ----------------
__global__ __launch_bounds__(256) void hist_kernel(const int* __restrict__ ei, int* __restrict__ deg)
{
    int e = blockIdx.x * 256 + threadIdx.x;
    if (e < EE) atomicAdd(&deg[ei[EE + e]], 1);
}

__global__ __launch_bounds__(256) void scan1(const int* __restrict__ deg,
                                             int* __restrict__ start, int* __restrict__ bsum)
{
    __shared__ int buf[256];
    int tid = threadIdx.x;
    int i = blockIdx.x*256 + tid;
    int v = (i < NN) ? deg[i] : 0;
    buf[tid] = v; __syncthreads();
    #pragma unroll
    for (int off = 1; off < 256; off <<= 1) {
        int t = (tid >= off) ? buf[tid-off] : 0;
        __syncthreads(); buf[tid] += t; __syncthreads();
    }
    if (i < NN) start[i] = buf[tid] - v;
    if (tid == 255) bsum[blockIdx.x] = buf[255];
}
__global__ __launch_bounds__(256) void scan2(int* __restrict__ bsum, int nb)
{
    __shared__ int buf[256];
    int tid = threadIdx.x;
    int v = (tid < nb) ? bsum[tid] : 0;
    buf[tid] = v; __syncthreads();
    #pragma unroll
    for (int off = 1; off < 256; off <<= 1) {
        int t = (tid >= off) ? buf[tid-off] : 0;
        __syncthreads(); buf[tid] += t; __syncthreads();
    }
    if (tid < nb) bsum[tid] = buf[tid] - v;
}
__global__ __launch_bounds__(256) void scan3(int* __restrict__ start, const int* __restrict__ bsum,
                                             int* __restrict__ cursor)
{
    int i = blockIdx.x*256 + threadIdx.x;
    if (i < NN) { int v = start[i] + bsum[blockIdx.x]; start[i] = v; cursor[i] = v; }
    if (i == 0) start[NN] = EE;
}

// ---------------- fused geometry + scatter: 16B packed edge record ----------------
__global__ __launch_bounds__(256) void geom_scatter(
    const float* __restrict__ pos, const int* __restrict__ ei, const float* __restrict__ shift,
    int* __restrict__ cursor, int4* __restrict__ edata)
{
    int e = blockIdx.x * 256 + threadIdx.x;
    if (e >= EE) return;
    int s = ei[e], d = ei[EE + e];
    float vx = pos[d*3+0] - pos[s*3+0] + shift[e*3+0];
    float vy = pos[d*3+1] - pos[s*3+1] + shift[e*3+1];
    float vz = pos[d*3+2] - pos[s*3+2] + shift[e*3+2];
    float r = sqrtf(vx*vx + vy*vy + vz*vz);
    float inv = 1.0f / (r + 1e-9f);
    float x = vx*inv, y = vy*inv, z = vz*inv;
    int p = atomicAdd(&cursor[d], 1);
    __half2 xy = __floats2half2_rn(x, y);
    __half2 z0 = __floats2half2_rn(z, 0.0f);
    int4 rec;
    rec.x = s;
    rec.y = __float_as_int(r);
    rec.z = *(const int*)&xy;
    rec.w = *(const int*)&z0;
    edata[p] = rec;
}

// ---------------- radial features on the bin grid (f32, NB+1 bins) ----------------
__global__ __launch_bounds__(128) void build_rf(
    const float* __restrict__ rw1, const float* __restrict__ rb1,
    const float* __restrict__ rw2, const float* __restrict__ rb2,
    float* __restrict__ rfall)
{
    int idx = blockIdx.x;
    int L = idx / (NB+1), bin = idx % (NB+1);
    float r = bin * (RTMAX / NB);
    int t = threadIdx.x;
    __shared__ float h1[64];
    if (t < 64) {
        float s = rb1[L*64 + t];
        #pragma unroll
        for (int i = 0; i < 10; i++) { float a = 1.8f*r - (float)i; s += __expf(-a*a) * rw1[L*640 + i*64 + t]; }
        h1[t] = silu(s);
    }
    __syncthreads();
    if (t < 112) {
        float s = rb2[L*112 + t];
        #pragma unroll 8
        for (int k = 0; k < 64; k++) s += h1[k] * rw2[(size_t)L*7168 + k*112 + t];
        rfall[(size_t)idx*112 + t] = s * 0.25f;
    }
}

// pack (delta form): tabpack[L][bin][lane] = { half2(A_base,A_delta), half2(B_base,B_delta) }
__global__ __launch_bounds__(256) void pack_tab(
    const float* __restrict__ rfall, uint2* __restrict__ tabpack)
{
    int t = blockIdx.x*256 + threadIdx.x;
    if (t >= 4*NB*64) return;
    int lane = t & 63;
    int rest = t >> 6;
    int L = rest / NB, bin = rest % NB;
    const float* lo = rfall + (size_t)(L*(NB+1) + bin)*112;
    const float* hi = lo + 112;
    float aLo = lo[lane], aHi = hi[lane];
    float bLo = (lane < 48) ? lo[64+lane] : 0.0f;
    float bHi = (lane < 48) ? hi[64+lane] : 0.0f;
    __half2 ha = __floats2half2_rn(aLo, aHi - aLo);
    __half2 hb = __floats2half2_rn(bLo, bHi - bLo);
    uint2 o;
    o.x = *(const unsigned*)&ha;
    o.y = *(const unsigned*)&hb;
    tabpack[t] = o;
}

// ---------------- init: h f32 [NNP][256] + packed P0 ----------------
__global__ __launch_bounds__(256) void init_hp32(
    const int* __restrict__ z, const float* __restrict__ emb,
    const float* __restrict__ pt, float* __restrict__ hG, unsigned* __restrict__ Ppack)
{
    int n = blockIdx.x; int j = threadIdx.x;
    int zz = z[n];
    hG[(size_t)n*256 + j] = (j < 64) ? emb[zz*64 + j] : 0.0f;
    if (j < 64) {
        float a = pt[zz*112 + j];
        float b = (j < 48) ? pt[zz*112 + 64 + j] : 0.0f;
        __half2 hp = __floats2half2_rn(a, b);
        Ppack[(size_t)n*64 + j] = *(const unsigned*)&hp;
    }
}

// ---------------- aggregation: 2 nodes per wave; 12-float edge rows, b128 consume ----------------
// row: [boff, poff, fr, sh7 | sh0, sh1, sh2, 0 | sh3, sh4, sh5, sh6]
__global__ __launch_bounds__(256) void agg_kernel(
    const unsigned* __restrict__ Ppack, const int4* __restrict__ edata,
    const int* __restrict__ start, const uint2* __restrict__ tabp,
    float* __restrict__ acc)
{
    int lane = threadIdx.x & 63;
    int wv   = threadIdx.x >> 6;
    int nA = blockIdx.x*(WPB*2) + wv*2;
    int nB = nA + 1;

    __shared__ float ebuf_s[WPB][2][16*12];
    __shared__ float accb_s[WPB][2][240];

    int p0A = start[nA], p1A = start[nA+1];
    int p1B = start[nB+1];
    float aS_A = 0.0f, aS_B = 0.0f;
    float aB_A[5] = {0,0,0,0,0};
    float aB_B[5] = {0,0,0,0,0};
    bool hasB = lane < 48;
    bool isT  = lane >= 32;                  // tensor group (5 comps)
    int shqoff = isT ? 8 : 4;                // float offset of this group's sh quad
    const float binscale = (float)NB / RTMAX;
    const float C3 = 1.7320508075688772f, C15 = 3.872983346207417f, C5 = 2.23606797749979f;

    const char* tabc = (const char*)tabp;
    const char* Pc   = (const char*)Ppack;
    int lane8 = lane*8, lane4 = lane*4;

    int baseA = p0A, baseB = p1A;
    while (baseA < p1A || baseB < p1B) {
        int cntA = p1A - baseA; cntA = cntA < 0 ? 0 : (cntA > 16 ? 16 : cntA);
        int cntB = p1B - baseB; cntB = cntB < 0 ? 0 : (cntB > 16 ? 16 : cntB);
        #pragma unroll
        for (int s = 0; s < 2; s++) {
            int cnt  = s ? cntB : cntA;
            int base = s ? baseB : baseA;
            if (lane < cnt) {
                int4 rec = edata[base + lane];
                float f = fminf(__int_as_float(rec.y) * binscale, (float)NB - 0.5f);
                int b = (int)f;
                float fr = f - (float)b;
                __half2 xy = *(const __half2*)&rec.z;
                __half2 z0 = *(const __half2*)&rec.w;
                float x = __half2float(xy.x), y = __half2float(xy.y), z = __half2float(z0.x);
                float4* v4 = (float4*)(ebuf_s[wv][s] + lane*12);
                v4[0] = make_float4(__int_as_float(b*512), __int_as_float(rec.x*256), fr,
                                    0.5f*C15*(x*x - y*y));
                v4[1] = make_float4(C3*x, C3*y, C3*z, 0.0f);
                v4[2] = make_float4(C15*x*y, C15*y*z, 0.5f*C5*(3.0f*z*z - 1.0f), C15*x*z);
            }
        }
        asm volatile("s_waitcnt lgkmcnt(0)" ::: "memory");
        #pragma unroll
        for (int s = 0; s < 2; s++) {
            int cnt = s ? cntB : cntA;
            const float* eb = ebuf_s[wv][s];
            float aS_l = 0.0f;
            float aB_l[5] = {0,0,0,0,0};
            #pragma unroll 4
            for (int e = 0; e < 16; e++) {
                if (e < cnt) {
                    const float* ep = eb + e*12;
                    float4 md = *(const float4*)ep;                    // b128
                    int boff = __float_as_int(md.x);
                    int poff = __float_as_int(md.y);
                    float fr = md.z;
                    uint2 tt = *(const uint2*)(tabc + boff + lane8);
                    unsigned pv = *(const unsigned*)(Pc + poff + lane4);
                    __half2 ha = *(const __half2*)&tt.x;
                    __half2 hp = *(const __half2*)&pv;
                    float rfA = __half2float(ha.x) + __half2float(ha.y)*fr;
                    aS_l += rfA * __half2float(hp.x);
                    if (hasB) {
                        float4 sq = *(const float4*)(ep + shqoff);     // b128
                        __half2 hb = *(const __half2*)&tt.y;
                        float rfB = __half2float(hb.x) + __half2float(hb.y)*fr;
                        float msg = rfB * __half2float(hp.y);
                        aB_l[0] += msg * sq.x;
                        aB_l[1] += msg * sq.y;
                        aB_l[2] += msg * sq.z;
                        if (isT) { aB_l[3] += msg * sq.w; aB_l[4] += msg * md.w; }
                    }
                }
            }
            if (s == 0) {
                aS_A += aS_l;
                #pragma unroll
                for (int d = 0; d < 5; d++) aB_A[d] += aB_l[d];
            } else {
                aS_B += aS_l;
                #pragma unroll
                for (int d = 0; d < 5; d++) aB_B[d] += aB_l[d];
            }
        }
        asm volatile("s_waitcnt lgkmcnt(0)" ::: "memory");
        baseA += 16; baseB += 16;
    }

    // stage into LDS in PERMUTED channel layout
    #pragma unroll
    for (int s = 0; s < 2; s++) {
        float* ab = accb_s[wv][s];
        ab[lane] = s ? aS_B : aS_A;
        const float* aB = s ? aB_B : aB_A;
        if (lane < 32) {
            #pragma unroll
            for (int d = 0; d < 3; d++) ab[64 + 32*d + lane] = aB[d];
        } else if (lane < 48) {
            #pragma unroll
            for (int d = 0; d < 5; d++) ab[160 + 16*d + (lane-32)] = aB[d];
        }
    }
    asm volatile("s_waitcnt lgkmcnt(0)" ::: "memory");
    #pragma unroll
    for (int s = 0; s < 2; s++) {
        float* arow = acc + (size_t)(nA + s)*240;
        const float* ab = accb_s[wv][s];
        #pragma unroll
        for (int c = lane; c < 240; c += 64) arow[c] = ab[c];
    }
}

// ---------------- MFMA node update + projection (h stays f32) ----------------
__global__ __launch_bounds__(256) void update_kernel(
    float* __restrict__ hG, const float* __restrict__ acc,
    const float* __restrict__ s0Tp, const float* __restrict__ s1Tp, const float* __restrict__ s2Tp,
    const float* __restrict__ wpTp, unsigned* __restrict__ Pnext, int hasNext)
{
    __shared__ _Float16 w0[64*72];
    __shared__ _Float16 w1[32*40];
    __shared__ _Float16 w2[16*40];
    __shared__ _Float16 wpl[112*72];
    __shared__ _Float16 sn[64*72];
    __shared__ _Float16 pbuf[64*120];

    int tid = threadIdx.x;
    int lane = tid & 63, wv = tid >> 6;
    int m = lane & 15, quad = lane >> 4;
    int nblk0 = blockIdx.x * 64;
    int n0 = nblk0 + wv*16;

    for (int i = tid; i < 64*72; i += 256) w0[i] = (_Float16)s0Tp[i];
    for (int i = tid; i < 32*40; i += 256) w1[i] = (_Float16)s1Tp[i];
    for (int i = tid; i < 16*40; i += 256) w2[i] = (_Float16)s2Tp[i];
    for (int i = tid; i < 112*72; i += 256) wpl[i] = (_Float16)wpTp[i];
    __syncthreads();

    size_t hrowm = (size_t)(n0 + m)*256;
    size_t arow0 = (size_t)(n0 + quad*4)*240;
    size_t orow0 = (size_t)(n0 + quad*4)*256;

#define LD8(OFF) ({ \
        float4 v0_ = *(const float4*)(hG + (OFF)); \
        float4 v1_ = *(const float4*)(hG + (OFF) + 4); \
        half8 h_; \
        h_[0] = (_Float16)v0_.x; h_[1] = (_Float16)v0_.y; \
        h_[2] = (_Float16)v0_.z; h_[3] = (_Float16)v0_.w; \
        h_[4] = (_Float16)v1_.x; h_[5] = (_Float16)v1_.y; \
        h_[6] = (_Float16)v1_.z; h_[7] = (_Float16)v1_.w; h_; })

    // ---- GEMM0: scalar block (cols 0..63, K 0..63) ----
    {
        half8 a0 = LD8(hrowm + 0  + quad*8);
        half8 a1 = LD8(hrowm + 32 + quad*8);
        #pragma unroll
        for (int t = 0; t < 4; t++) {
            int cb = 16*t;
            floatx4 c;
            #pragma unroll
            for (int r = 0; r < 4; r++) c[r] = acc[arow0 + (size_t)r*240 + cb + m];
            c = __builtin_amdgcn_mfma_f32_16x16x32_f16(a0, *(const half8*)&w0[(cb+m)*72 + 0  + quad*8], c, 0, 0, 0);
            c = __builtin_amdgcn_mfma_f32_16x16x32_f16(a1, *(const half8*)&w0[(cb+m)*72 + 32 + quad*8], c, 0, 0, 0);
            #pragma unroll
            for (int r = 0; r < 4; r++) {
                float u = silu(c[r]);
                hG[orow0 + (size_t)r*256 + cb + m] = u;
                sn[(wv*16 + quad*4 + r)*72 + cb + m] = (_Float16)u;
            }
        }
    }
    // ---- GEMM1: vector blocks d=0..2 ----
    #pragma unroll
    for (int d = 0; d < 3; d++) {
        int kb = 64 + 32*d;
        half8 av = LD8(hrowm + kb + quad*8);
        #pragma unroll
        for (int t = 0; t < 2; t++) {
            int cb = kb + 16*t;
            floatx4 c;
            #pragma unroll
            for (int r = 0; r < 4; r++) c[r] = acc[arow0 + (size_t)r*240 + cb + m];
            c = __builtin_amdgcn_mfma_f32_16x16x32_f16(av, *(const half8*)&w1[(16*t+m)*40 + quad*8], c, 0, 0, 0);
            #pragma unroll
            for (int r = 0; r < 4; r++) hG[orow0 + (size_t)r*256 + cb + m] = c[r];
        }
    }
    // ---- GEMM2: tensor blocks e=0..4 ----
    #pragma unroll
    for (int e = 0; e < 5; e++) {
        int kb = 160 + 16*e;
        half8 at_ = LD8(hrowm + kb + quad*8);
        floatx4 c;
        #pragma unroll
        for (int r = 0; r < 4; r++) c[r] = acc[arow0 + (size_t)r*240 + kb + m];
        c = __builtin_amdgcn_mfma_f32_16x16x32_f16(at_, *(const half8*)&w2[m*40 + quad*8], c, 0, 0, 0);
        #pragma unroll
        for (int r = 0; r < 4; r++) hG[orow0 + (size_t)r*256 + kb + m] = c[r];
    }

    // ---- projection P = s_new @ wpc_next ----
    if (hasNext) {
        asm volatile("s_waitcnt lgkmcnt(0)" ::: "memory");
        half8 p0 = *(const half8*)&sn[(wv*16 + m)*72 + 0  + quad*8];
        half8 p1 = *(const half8*)&sn[(wv*16 + m)*72 + 32 + quad*8];
        #pragma unroll
        for (int t = 0; t < 7; t++) {
            floatx4 c = {0.0f, 0.0f, 0.0f, 0.0f};
            c = __builtin_amdgcn_mfma_f32_16x16x32_f16(p0, *(const half8*)&wpl[(16*t+m)*72 + 0  + quad*8], c, 0, 0, 0);
            c = __builtin_amdgcn_mfma_f32_16x16x32_f16(p1, *(const half8*)&wpl[(16*t+m)*72 + 32 + quad*8], c, 0, 0, 0);
            #pragma unroll
            for (int r = 0; r < 4; r++) pbuf[(wv*16 + quad*4 + r)*120 + 16*t + m] = (_Float16)c[r];
        }
        __syncthreads();
        for (int i = tid; i < 64*64; i += 256) {
            int node = i >> 6, j = i & 63;
            _Float16 aa = pbuf[node*120 + j];
            _Float16 bb = (j < 48) ? pbuf[node*120 + 64 + j] : (_Float16)0.0f;
            unsigned lo = *(const unsigned short*)&aa;
            unsigned hi = *(const unsigned short*)&bb;
            if (nblk0 + node < NN) Pnext[(size_t)(nblk0 + node)*64 + j] = lo | (hi << 16);
        }
    }
#undef LD8
}

// ---------------- merged readout A+B (kq is block-local) ----------------
__global__ __launch_bounds__(64) void readout_ab(
    const float* __restrict__ hG, const float* __restrict__ wq, const float* __restrict__ wk,
    const float* __restrict__ wv, float* __restrict__ zr)
{
    int b = blockIdx.x; int j = threadIdx.x;
    int na = 50 * b;
    const float* hr = hG + (size_t)na*256;
    __shared__ float sa[64], qv[64], kqv[64];
    __shared__ float hblk[64][51];
    __shared__ float at[64], hbar[64];
    sa[j] = hr[j];
    if (j < 50) {
        const float* hrr = hG + (size_t)(50*b + j)*256;
        #pragma unroll 8
        for (int k = 0; k < 64; k++) hblk[k][j] = hrr[k];
    }
    __syncthreads();
    float q = 0.0f;
    #pragma unroll 8
    for (int k = 0; k < 64; k++) q += sa[k] * wq[k*64 + j];
    qv[j] = q;
    zr[b*176 + j] = sa[j];
    if (j < 32) {
        float nv = 0.0f;
        #pragma unroll
        for (int c = 0; c < 3; c++) { float v = hr[64 + 32*c + j]; nv += v*v; }
        zr[b*176 + 128 + j] = nv;
    }
    if (j < 16) {
        float nt = 0.0f;
        #pragma unroll
        for (int c = 0; c < 5; c++) { float v = hr[160 + 16*c + j]; nt += v*v; }
        zr[b*176 + 160 + j] = nt;
    }
    __syncthreads();
    float s = 0.0f;
    #pragma unroll 8
    for (int jj = 0; jj < 64; jj++) s += wk[j*64 + jj] * qv[jj];
    kqv[j] = s;
    __syncthreads();
    float logit = -1e30f;
    if (j < 50) {
        float t = 0.0f;
        #pragma unroll 8
        for (int k = 0; k < 64; k++) t += hblk[k][j] * kqv[k];
        logit = t * 0.125f;
    }
    float mx = logit;
    for (int o = 32; o; o >>= 1) mx = fmaxf(mx, __shfl_xor(mx, o));
    float ex = (j < 50) ? __expf(logit - mx) : 0.0f;
    float den = ex;
    for (int o = 32; o; o >>= 1) den += __shfl_xor(den, o);
    at[j] = ex / den;
    __syncthreads();
    float hb = 0.0f;
    #pragma unroll 1
    for (int i = 0; i < 50; i++) hb += at[i] * hblk[j][i];
    hbar[j] = hb;
    __syncthreads();
    float c = 0.0f;
    #pragma unroll 8
    for (int k = 0; k < 64; k++) c += hbar[k] * wv[k*64 + j];
    zr[b*176 + 64 + j] = c;
}

// ---------------- readout C ----------------
__global__ __launch_bounds__(128) void readout_c(
    const float* __restrict__ zr, const float* __restrict__ m1, const float* __restrict__ mb1,
    const float* __restrict__ m2, const float* __restrict__ mb2, float* __restrict__ out)
{
    int b = blockIdx.x; int j = threadIdx.x;
    __shared__ float z[176], tb[128];
    for (int t = j; t < 176; t += 128) z[t] = zr[b*176 + t];
    __syncthreads();
    float a = mb1[j];
    #pragma unroll 8
    for (int k = 0; k < 176; k++) a += z[k] * m1[k*128 + j];
    tb[j] = silu(a);
    __syncthreads();
    float o = mb2[j];
    #pragma unroll 8
    for (int k = 0; k < 128; k++) o += tb[k] * m2[k*128 + j];
    out[b*128 + j] = o;
}

extern "C" void kernel_launch(void* const* d_in, const int* in_sizes, int n_in,
                              void* d_out, int out_size, void* d_ws, size_t ws_size,
                              hipStream_t stream)
{
    const int*   z     = (const int*)  d_in[0];
    const float* pos   = (const float*)d_in[1];
    const int*   ei    = (const int*)  d_in[2];
    const float* shift = (const float*)d_in[3];
    const float* emb = (const float*)d_in[6];
    const float* rw1 = (const float*)d_in[7];
    const float* rb1 = (const float*)d_in[8];
    const float* rw2 = (const float*)d_in[9];
    const float* rb2 = (const float*)d_in[10];
    const float* wp0 = (const float*)d_in[11];
    const float* wp1 = (const float*)d_in[12];
    const float* wp2 = (const float*)d_in[13];
    const float* s0  = (const float*)d_in[14];
    const float* s1  = (const float*)d_in[15];
    const float* s2  = (const float*)d_in[16];
    const float* wq  = (const float*)d_in[17];
    const float* wk  = (const float*)d_in[18];
    const float* wv  = (const float*)d_in[19];
    const float* m1  = (const float*)d_in[20];
    const float* mb1 = (const float*)d_in[21];
    const float* m2  = (const float*)d_in[22];
    const float* mb2 = (const float*)d_in[23];

    float* ws = (float*)d_ws;
    size_t off = 0;
    int4*  edata = (int4*)(ws + off); off += (size_t)4*EE;
    int*   deg    = (int*)(ws + off); off += NN;
    int*   startA = (int*)(ws + off); off += NN + 4;
    int*   cursor = (int*)(ws + off); off += NN;
    int*   bsum   = (int*)(ws + off); off += 256;
    float* hG  = ws + off; off += (size_t)NNP*256;   // f32 [NNP][256]
    float* acc = ws + off; off += (size_t)NNP*240;
    unsigned* Pa = (unsigned*)(ws + off); off += (size_t)NNP*64;
    unsigned* Pb = (unsigned*)(ws + off); off += (size_t)NNP*64;
    uint2* tabpack = (uint2*)(ws + off); off += (size_t)4*NB*64*2;
    float* wpc = ws + off; off += 4*64*112;
    float* pt  = ws + off; off += 100*112;
    float* s0Tp = ws + off; off += 4*4608;
    float* s1Tp = ws + off; off += 4*1280;
    float* s2Tp = ws + off; off += 4*640;
    float* wpTp = ws + off; off += 4*8064;
    float* zr  = ws + off; off += BB*176;
    float* rfall = acc;    // overlay: rfall consumed by pack_tab before agg writes acc

    prep_a<<<(NN + 255)/256, 256, 0, stream>>>(wp0, wp1, wp2, s0, s1, s2,
                                               wpc, s0Tp, s1Tp, s2Tp, deg);
    prep_b<<<(4*8064 + 255)/256, 256, 0, stream>>>(wpc, emb, wpTp, pt);

    hist_kernel<<<(EE + 255)/256, 256, 0, stream>>>(ei, deg);
    const int NSB = (NN + 255)/256;
    scan1<<<NSB, 256, 0, stream>>>(deg, startA, bsum);
    scan2<<<1, 256, 0, stream>>>(bsum, NSB);
    scan3<<<NSB, 256, 0, stream>>>(startA, bsum, cursor);
    geom_scatter<<<(EE + 255)/256, 256, 0, stream>>>(pos, ei, shift, cursor, edata);

    build_rf<<<4*(NB+1), 128, 0, stream>>>(rw1, rb1, rw2, rb2, rfall);
    pack_tab<<<(4*NB*64 + 255)/256, 256, 0, stream>>>(rfall, tabpack);
    init_hp32<<<NN, 256, 0, stream>>>(z, emb, pt, hG, Pa);

    unsigned* Pcur = Pa; unsigned* Pnxt = Pb;
    for (int L = 0; L < 4; L++) {
        int hasNext = (L < 3) ? 1 : 0;
        agg_kernel<<<NN/(WPB*2), 256, 0, stream>>>(
            Pcur, edata, startA, tabpack + (size_t)L*NB*64, acc);
        update_kernel<<<NNP/64, 256, 0, stream>>>(
            hG, acc, s0Tp + L*4608, s1Tp + L*1280, s2Tp + L*640,
            wpTp + (hasNext ? (L+1)*8064 : 0), Pnxt, hasNext);
        unsigned* tmp = Pcur; Pcur = Pnxt; Pnxt = tmp;
    }

    readout_ab<<<BB, 64, 0, stream>>>(hG, wq, wk, wv, zr);
    readout_c<<<BB, 128, 0, stream>>>(zr, m1, mb1, m2, mb2, (float*)d_out);
}